// Round 17
// baseline (111.278 us; speedup 1.0000x reference)
//
#include <hip/hip_runtime.h>
#include <math.h>

#define NBATCH 4
#define NPTS   8192
#define KNN    8
#define NCH    4096
#define SLICES 16
#define SLEN   512               // candidates per slice-wave
#define NWIN   8                 // windows per slice
#define WLEN   64                // candidates per window
#define CTR_OFF 56
#define PB_OFF  256                                  // f32 pair buffer, 32B/pair
#define SCAN_BLOCKS (NBATCH * (NPTS / 64))           // 512

typedef float v2f __attribute__((ext_vector_type(2)));

__device__ __forceinline__ unsigned umin32(unsigned a, unsigned b) { return a < b ? a : b; }

// single-block insert: 8 instrs, bd pinned via tied "+v", in-place descending
// order reads only pre-block values => depth-1 sorted insert (ascending top-8).
// Used ONLY in the merge phases (not the hot scan loop).
#define INSERT8(bd, key)                                          \
    asm("v_med3_u32 %7, %8, %6, %7\n\t"                           \
        "v_med3_u32 %6, %8, %5, %6\n\t"                           \
        "v_med3_u32 %5, %8, %4, %5\n\t"                           \
        "v_med3_u32 %4, %8, %3, %4\n\t"                           \
        "v_med3_u32 %3, %8, %2, %3\n\t"                           \
        "v_med3_u32 %2, %8, %1, %2\n\t"                           \
        "v_med3_u32 %1, %8, %0, %1\n\t"                           \
        "v_min_u32  %0, %0, %8"                                   \
        : "+v"(bd[0]), "+v"(bd[1]), "+v"(bd[2]), "+v"(bd[3]),     \
          "+v"(bd[4]), "+v"(bd[5]), "+v"(bd[6]), "+v"(bd[7])      \
        : "v"(key))

// prep (512 thr x 146 blocks): [0,32) pred->f32 pair buffer; [32,80) recon MSE
// (float4); [80,82) percep MSE (float4); [82,146) boundary on RAW c2 (64 blocks
// x 64 queries, 8 waves x 512 candidates via wave-uniform scalar loads,
// difference-form d^2 — no staging buffer, no intra-kernel dependency).
// acc/ctr zeroed by hipMemsetAsync before this kernel.
__global__ __launch_bounds__(512) void prep_kernel(const float* __restrict__ pts,
                                                   const float* __restrict__ c2,
                                                   const float* __restrict__ a,
                                                   const float* __restrict__ bt,
                                                   const float* __restrict__ a2,
                                                   const float* __restrict__ b2,
                                                   const float* __restrict__ c1,
                                                   float* __restrict__ pb,
                                                   double* __restrict__ acc) {
    __shared__ float red[512];
    const int t = threadIdx.x;
    const int blk = blockIdx.x;
    if (blk < 32) {
        const int pi = blk * 512 + t;
        const float* s = pts + (size_t)pi * 6;
        const float x0 = s[0], y0 = s[1], z0 = s[2];
        const float x1 = s[3], y1 = s[4], z1 = s[5];
        float4* o = reinterpret_cast<float4*>(pb + (size_t)pi * 8);
        o[0] = make_float4(x0, x1, y0, y1);
        o[1] = make_float4(z0, z1, x0 * x0 + y0 * y0 + z0 * z0,
                                   x1 * x1 + y1 * y1 + z1 * z1);
        return;
    }
    if (blk < 82) {
        float s;
        int which;
        if (blk < 80) {
            which = 0;
            const int i = (blk - 32) * 512 + t;
            const float4 va = reinterpret_cast<const float4*>(a)[i];
            const float4 vb = reinterpret_cast<const float4*>(bt)[i];
            const float dx = va.x - vb.x, dy = va.y - vb.y;
            const float dz = va.z - vb.z, dw = va.w - vb.w;
            s = dx * dx + dy * dy + dz * dz + dw * dw;
        } else {
            which = 1;
            const int i = (blk - 80) * 512 + t;
            const float4 va = reinterpret_cast<const float4*>(a2)[i];
            const float4 vb = reinterpret_cast<const float4*>(b2)[i];
            const float dx = va.x - vb.x, dy = va.y - vb.y;
            const float dz = va.z - vb.z, dw = va.w - vb.w;
            s = dx * dx + dy * dy + dz * dz + dw * dw;
        }
#pragma unroll
        for (int o = 32; o > 0; o >>= 1) s += __shfl_down(s, o, 64);
        if ((t & 63) == 0) red[t >> 6] = s;
        __syncthreads();
        if (t == 0) {
            float bs = 0.f;
#pragma unroll
            for (int i = 0; i < 8; ++i) bs += red[i];
            atomicAdd(&acc[which], (double)bs);
        }
        return;
    }
    // boundary: 64 queries per block (one per lane), 8 waves x 512 raw c2 pts
    const int lane = t & 63;
    const int w8 = __builtin_amdgcn_readfirstlane(t >> 6);   // 0..7
    const int qi = (blk - 82) * 64 + lane;
    const float qx = c1[qi * 3 + 0];
    const float qy = c1[qi * 3 + 1];
    const float qz = c1[qi * 3 + 2];
    float m = 3.0e38f;
    const float* __restrict__ Sp = c2 + (size_t)w8 * 512 * 3;   // uniform base
#pragma unroll 8
    for (int j = 0; j < 512; ++j) {
        const float dx = Sp[j * 3 + 0] - qx;
        const float dy = Sp[j * 3 + 1] - qy;
        const float dz = Sp[j * 3 + 2] - qz;
        m = fminf(m, fmaf(dx, dx, fmaf(dy, dy, dz * dz)));
    }
    red[w8 * 64 + lane] = m;
    __syncthreads();
    if (w8 == 0) {
        float mm = red[lane];
#pragma unroll
        for (int s = 1; s < 8; ++s) mm = fminf(mm, red[s * 64 + lane]);
        const float d = sqrtf(mm);
        const bool in = d < 0.1f;
        float sc = in ? d : 0.f;
        float sn = in ? 1.f : 0.f;
#pragma unroll
        for (int o = 32; o > 0; o >>= 1) {
            sc += __shfl_down(sc, o, 64);
            sn += __shfl_down(sn, o, 64);
        }
        if (lane == 0) {
            atomicAdd(&acc[3], (double)sc);
            atomicAdd(&acc[4], (double)sn);
        }
    }
}

// Main kernel: EXACT round-11 continuity scan, 512 blocks x 1024 thr (perfect
// 2 blocks/CU). 16 slice-waves x 64 shared queries; each wave scans its
// 512-candidate slice as 8 windows of 64 via wave-uniform scalar loads (plain
// C, compiler-pipelined s_load_dwordx4 batches). Window min keys (26-bit d2 |
// 6-bit idx) -> exact med3 top-8 merge (self filtered by index), closed-form
// deviation sum. Last-finished block writes the 5 outputs.
__global__ __launch_bounds__(1024, 8) void main_kernel(const float* __restrict__ pb,
                                                       double* __restrict__ acc,
                                                       unsigned* __restrict__ ctr,
                                                       float* __restrict__ out) {
    __shared__ unsigned mrg[SLICES][KNN][64];   // 32 KB, lane-consecutive
    const int t    = threadIdx.x;
    const int lane = t & 63;
    const int w    = __builtin_amdgcn_readfirstlane(t >> 6);   // slice id (SGPR)
    const int nqw  = NPTS / 64;
    const int b    = blockIdx.x / nqw;
    const int q0   = (blockIdx.x % nqw) * 64;
    const float* __restrict__ B = pb + (size_t)b * (NPTS / 2) * 8;

    const int qi = q0 + lane;
    const float* qp = B + (size_t)(qi >> 1) * 8;
    const int e = qi & 1;
    const float qx = qp[0 + e], qy = qp[2 + e], qz = qp[4 + e], qw = qp[6 + e];
    const v2f qnp2 = {qw + 1e-6f, qw + 1e-6f};
    const v2f m2x2 = {-2.f * qx, -2.f * qx};
    const v2f m2y2 = {-2.f * qy, -2.f * qy};
    const v2f m2z2 = {-2.f * qz, -2.f * qz};

    const float* __restrict__ Sp = B + (size_t)w * SLEN * 4;
    const unsigned jb = (unsigned)(w * SLEN);
    unsigned keyout[NWIN];

#pragma unroll
    for (int wi = 0; wi < NWIN; ++wi) {
        const float* __restrict__ Wp = Sp + wi * (WLEN * 4);
        unsigned wmA = 0xFFFFFFFFu, wmB = 0xFFFFFFFFu;
#pragma unroll
        for (int j = 0; j < WLEN / 2; ++j) {
            const float4 ab = *reinterpret_cast<const float4*>(Wp + j * 8);      // x0 x1 y0 y1
            const float4 cd = *reinterpret_cast<const float4*>(Wp + j * 8 + 4);  // z0 z1 w0 w1
            const v2f xp = {ab.x, ab.y}, yp = {ab.z, ab.w};
            const v2f zp = {cd.x, cd.y}, wp = {cd.z, cd.w};
            v2f s2 = wp + qnp2;
            s2 = __builtin_elementwise_fma(zp, m2z2, s2);
            s2 = __builtin_elementwise_fma(yp, m2y2, s2);
            s2 = __builtin_elementwise_fma(xp, m2x2, s2);
            const unsigned k0 = (__float_as_uint(s2.x) & 0xFFFFFFC0u) | (unsigned)(2 * j);
            const unsigned k1 = (__float_as_uint(s2.y) & 0xFFFFFFC0u) | (unsigned)(2 * j + 1);
            wmA = umin32(wmA, k0);
            wmB = umin32(wmB, k1);
        }
        const unsigned wm = umin32(wmA, wmB);
        const unsigned base = jb + (unsigned)(wi * WLEN);   // scalar per window
        keyout[wi] = (wm & 0xFFFFE000u) | base | (wm & 63u);
    }

#pragma unroll
    for (int wi = 0; wi < NWIN; ++wi) mrg[w][wi][lane] = keyout[wi];
    __syncthreads();

    // stage 1: waves 0..3 each merge 4 slices' window minima (self filtered)
    if (w < 4) {
        const unsigned selfidx = (unsigned)qi;
        unsigned best[KNN];
#pragma unroll
        for (int s = 0; s < KNN; ++s) best[s] = 0xFFFFFFFFu;
        for (int sl = 4 * w; sl < 4 * w + 4; ++sl) {
#pragma unroll
            for (int u = 0; u < KNN; ++u) {
                unsigned key = mrg[sl][u][lane];
                key = ((key & 0x1FFFu) == selfidx) ? 0xFFFFFFFFu : key;
                INSERT8(best, key);
            }
        }
#pragma unroll
        for (int s = 0; s < KNN; ++s) mrg[4 * w][s][lane] = best[s];
    }
    __syncthreads();

    // stage 2: wave 0 merges the 4 partials; closed-form deviation sum
    if (w == 0) {
        unsigned best[KNN];
#pragma unroll
        for (int s = 0; s < KNN; ++s) best[s] = 0xFFFFFFFFu;
        for (int g = 0; g < 4; ++g) {
#pragma unroll
            for (int u = 0; u < KNN; ++u) {
                const unsigned key = mrg[4 * g][u][lane];
                INSERT8(best, key);
            }
        }
        float sx = 0.f, sy = 0.f, sz = 0.f, sw = 0.f;
#pragma unroll
        for (int s = 0; s < KNN; ++s) {
            const unsigned n = best[s] & 0x1FFFu;
            const float* np = B + (size_t)(n >> 1) * 8 + (n & 1);
            sx += np[0]; sy += np[2]; sz += np[4]; sw += np[6];
        }
        float ssum = sw - (sx * sx + sy * sy + sz * sz) * (1.f / KNN);
#pragma unroll
        for (int o = 32; o > 0; o >>= 1) ssum += __shfl_down(ssum, o, 64);
        if (lane == 0) atomicAdd(&acc[2], (double)ssum);
    }

    // last-done block finalizes the 5 outputs (prep finished before this kernel)
    __syncthreads();
    if (t == 0) {
        __threadfence();
        const unsigned old = atomicAdd(ctr, 1u);
        if (old == SCAN_BLOCKS - 1) {
            __threadfence();
            const double a0 = atomicAdd(&acc[0], 0.0);
            const double a1 = atomicAdd(&acc[1], 0.0);
            const double a2d = atomicAdd(&acc[2], 0.0);
            const double a3 = atomicAdd(&acc[3], 0.0);
            const double a4 = atomicAdd(&acc[4], 0.0);
            const double recon  = a0 / (double)(NBATCH * NPTS * 3);
            const double percep = a1 / 4096.0;
            const double cont   = a2d / (double)(NBATCH * NPTS * KNN);
            const double bnd    = (a4 > 0.0) ? a3 / ((a4 > 1.0) ? a4 : 1.0) : 0.0;
            const double total  = recon + 0.5 * percep + 0.5 * cont + bnd;
            out[0] = (float)recon;
            out[1] = (float)percep;
            out[2] = (float)cont;
            out[3] = (float)bnd;
            out[4] = (float)total;
        }
    }
}

extern "C" void kernel_launch(void* const* d_in, const int* in_sizes, int n_in,
                              void* d_out, int out_size, void* d_ws, size_t ws_size,
                              hipStream_t stream) {
    const float* pred = (const float*)d_in[0];
    const float* targ = (const float*)d_in[1];
    const float* pf   = (const float*)d_in[2];
    const float* tf   = (const float*)d_in[3];
    const float* c1   = (const float*)d_in[4];
    const float* c2   = (const float*)d_in[5];
    float* out  = (float*)d_out;
    double* acc = (double*)d_ws;
    unsigned* ctr = (unsigned*)((char*)d_ws + CTR_OFF);
    float* pb   = (float*)((char*)d_ws + PB_OFF);

    hipMemsetAsync(d_ws, 0, 64, stream);   // acc[0..4] + ctr
    hipLaunchKernelGGL(prep_kernel, dim3(146), dim3(512), 0, stream,
                       pred, c2, pred, targ, pf, tf, c1, pb, acc);
    hipLaunchKernelGGL(main_kernel, dim3(SCAN_BLOCKS), dim3(1024), 0, stream,
                       pb, acc, ctr, out);
}

// Round 18
// 72.796 us; speedup vs baseline: 1.5286x; 1.5286x over previous
//
#include <hip/hip_runtime.h>
#include <math.h>

#define NBATCH 4
#define NPTS   8192
#define KNN    8
#define NCH    4096
#define SLICES 16
#define SLEN   512               // candidates per slice-wave
#define NWIN   8                 // windows per slice
#define WLEN   64                // candidates per window
#define CTR_OFF 56
#define PB_OFF  256                                  // f32 pair buffer, 32B/pair
#define SCAN_BLOCKS (NBATCH * (NPTS / 64))           // 512

typedef float v2f __attribute__((ext_vector_type(2)));

__device__ __forceinline__ unsigned umin32(unsigned a, unsigned b) { return a < b ? a : b; }

// single-block insert: 8 instrs, bd pinned via tied "+v", in-place descending
// order reads only pre-block values => depth-1 sorted insert (ascending top-8).
// Used ONLY in the merge phases (not the hot scan loop).
#define INSERT8(bd, key)                                          \
    asm("v_med3_u32 %7, %8, %6, %7\n\t"                           \
        "v_med3_u32 %6, %8, %5, %6\n\t"                           \
        "v_med3_u32 %5, %8, %4, %5\n\t"                           \
        "v_med3_u32 %4, %8, %3, %4\n\t"                           \
        "v_med3_u32 %3, %8, %2, %3\n\t"                           \
        "v_med3_u32 %2, %8, %1, %2\n\t"                           \
        "v_med3_u32 %1, %8, %0, %1\n\t"                           \
        "v_min_u32  %0, %0, %8"                                   \
        : "+v"(bd[0]), "+v"(bd[1]), "+v"(bd[2]), "+v"(bd[3]),     \
          "+v"(bd[4]), "+v"(bd[5]), "+v"(bd[6]), "+v"(bd[7])      \
        : "v"(key))

// prep (512 thr x 146 blocks): [0,32) pred->f32 pair buffer; [32,80) recon MSE
// (float4); [80,82) percep MSE (float4); [82,146) boundary on RAW c2 via
// ALIGNED float4 loads + compile-time unpack (3 x dwordx4 per 4 candidates —
// the r6-verified pattern that lets the compiler batch s_load_dwordx4 deeply).
// acc/ctr zeroed by hipMemsetAsync before this kernel.
__global__ __launch_bounds__(512) void prep_kernel(const float* __restrict__ pts,
                                                   const float* __restrict__ c2,
                                                   const float* __restrict__ a,
                                                   const float* __restrict__ bt,
                                                   const float* __restrict__ a2,
                                                   const float* __restrict__ b2,
                                                   const float* __restrict__ c1,
                                                   float* __restrict__ pb,
                                                   double* __restrict__ acc) {
    __shared__ float red[512];
    const int t = threadIdx.x;
    const int blk = blockIdx.x;
    if (blk < 32) {
        const int pi = blk * 512 + t;
        const float* s = pts + (size_t)pi * 6;
        const float x0 = s[0], y0 = s[1], z0 = s[2];
        const float x1 = s[3], y1 = s[4], z1 = s[5];
        float4* o = reinterpret_cast<float4*>(pb + (size_t)pi * 8);
        o[0] = make_float4(x0, x1, y0, y1);
        o[1] = make_float4(z0, z1, x0 * x0 + y0 * y0 + z0 * z0,
                                   x1 * x1 + y1 * y1 + z1 * z1);
        return;
    }
    if (blk < 82) {
        float s;
        int which;
        if (blk < 80) {
            which = 0;
            const int i = (blk - 32) * 512 + t;
            const float4 va = reinterpret_cast<const float4*>(a)[i];
            const float4 vb = reinterpret_cast<const float4*>(bt)[i];
            const float dx = va.x - vb.x, dy = va.y - vb.y;
            const float dz = va.z - vb.z, dw = va.w - vb.w;
            s = dx * dx + dy * dy + dz * dz + dw * dw;
        } else {
            which = 1;
            const int i = (blk - 80) * 512 + t;
            const float4 va = reinterpret_cast<const float4*>(a2)[i];
            const float4 vb = reinterpret_cast<const float4*>(b2)[i];
            const float dx = va.x - vb.x, dy = va.y - vb.y;
            const float dz = va.z - vb.z, dw = va.w - vb.w;
            s = dx * dx + dy * dy + dz * dz + dw * dw;
        }
#pragma unroll
        for (int o = 32; o > 0; o >>= 1) s += __shfl_down(s, o, 64);
        if ((t & 63) == 0) red[t >> 6] = s;
        __syncthreads();
        if (t == 0) {
            float bs = 0.f;
#pragma unroll
            for (int i = 0; i < 8; ++i) bs += red[i];
            atomicAdd(&acc[which], (double)bs);
        }
        return;
    }
    // boundary: 64 queries per block (one per lane), 8 waves x 512 raw c2 pts,
    // aligned float4 wave-uniform loads + compile-time component unpack
    const int lane = t & 63;
    const int w8 = __builtin_amdgcn_readfirstlane(t >> 6);   // 0..7
    const int qi = (blk - 82) * 64 + lane;
    const float qx = c1[qi * 3 + 0];
    const float qy = c1[qi * 3 + 1];
    const float qz = c1[qi * 3 + 2];
    float m = 3.0e38f;
    const float* __restrict__ Sp = c2 + (size_t)w8 * 512 * 3;   // 6144B aligned
#define BCAND(CX, CY, CZ)                                                 \
    do {                                                                  \
        const float dx = (CX) - qx, dy = (CY) - qy, dz = (CZ) - qz;       \
        m = fminf(m, fmaf(dx, dx, fmaf(dy, dy, dz * dz)));                \
    } while (0)
#pragma unroll 8
    for (int j4 = 0; j4 < 512; j4 += 4) {
        const float4 u0 = *reinterpret_cast<const float4*>(Sp + j4 * 3 + 0);
        const float4 u1 = *reinterpret_cast<const float4*>(Sp + j4 * 3 + 4);
        const float4 u2 = *reinterpret_cast<const float4*>(Sp + j4 * 3 + 8);
        BCAND(u0.x, u0.y, u0.z);
        BCAND(u0.w, u1.x, u1.y);
        BCAND(u1.z, u1.w, u2.x);
        BCAND(u2.y, u2.z, u2.w);
    }
#undef BCAND
    red[w8 * 64 + lane] = m;
    __syncthreads();
    if (w8 == 0) {
        float mm = red[lane];
#pragma unroll
        for (int s = 1; s < 8; ++s) mm = fminf(mm, red[s * 64 + lane]);
        const float d = sqrtf(mm);
        const bool in = d < 0.1f;
        float sc = in ? d : 0.f;
        float sn = in ? 1.f : 0.f;
#pragma unroll
        for (int o = 32; o > 0; o >>= 1) {
            sc += __shfl_down(sc, o, 64);
            sn += __shfl_down(sn, o, 64);
        }
        if (lane == 0) {
            atomicAdd(&acc[3], (double)sc);
            atomicAdd(&acc[4], (double)sn);
        }
    }
}

// Main kernel: EXACT round-11 continuity scan, 512 blocks x 1024 thr (perfect
// 2 blocks/CU). 16 slice-waves x 64 shared queries; each wave scans its
// 512-candidate slice as 8 windows of 64 via wave-uniform scalar loads (plain
// C, compiler-pipelined s_load_dwordx4 batches). Window min keys (26-bit d2 |
// 6-bit idx) -> exact med3 top-8 merge (self filtered by index), closed-form
// deviation sum. Last-finished block writes the 5 outputs.
__global__ __launch_bounds__(1024, 8) void main_kernel(const float* __restrict__ pb,
                                                       double* __restrict__ acc,
                                                       unsigned* __restrict__ ctr,
                                                       float* __restrict__ out) {
    __shared__ unsigned mrg[SLICES][KNN][64];   // 32 KB, lane-consecutive
    const int t    = threadIdx.x;
    const int lane = t & 63;
    const int w    = __builtin_amdgcn_readfirstlane(t >> 6);   // slice id (SGPR)
    const int nqw  = NPTS / 64;
    const int b    = blockIdx.x / nqw;
    const int q0   = (blockIdx.x % nqw) * 64;
    const float* __restrict__ B = pb + (size_t)b * (NPTS / 2) * 8;

    const int qi = q0 + lane;
    const float* qp = B + (size_t)(qi >> 1) * 8;
    const int e = qi & 1;
    const float qx = qp[0 + e], qy = qp[2 + e], qz = qp[4 + e], qw = qp[6 + e];
    const v2f qnp2 = {qw + 1e-6f, qw + 1e-6f};
    const v2f m2x2 = {-2.f * qx, -2.f * qx};
    const v2f m2y2 = {-2.f * qy, -2.f * qy};
    const v2f m2z2 = {-2.f * qz, -2.f * qz};

    const float* __restrict__ Sp = B + (size_t)w * SLEN * 4;
    const unsigned jb = (unsigned)(w * SLEN);
    unsigned keyout[NWIN];

#pragma unroll
    for (int wi = 0; wi < NWIN; ++wi) {
        const float* __restrict__ Wp = Sp + wi * (WLEN * 4);
        unsigned wmA = 0xFFFFFFFFu, wmB = 0xFFFFFFFFu;
#pragma unroll
        for (int j = 0; j < WLEN / 2; ++j) {
            const float4 ab = *reinterpret_cast<const float4*>(Wp + j * 8);      // x0 x1 y0 y1
            const float4 cd = *reinterpret_cast<const float4*>(Wp + j * 8 + 4);  // z0 z1 w0 w1
            const v2f xp = {ab.x, ab.y}, yp = {ab.z, ab.w};
            const v2f zp = {cd.x, cd.y}, wp = {cd.z, cd.w};
            v2f s2 = wp + qnp2;
            s2 = __builtin_elementwise_fma(zp, m2z2, s2);
            s2 = __builtin_elementwise_fma(yp, m2y2, s2);
            s2 = __builtin_elementwise_fma(xp, m2x2, s2);
            const unsigned k0 = (__float_as_uint(s2.x) & 0xFFFFFFC0u) | (unsigned)(2 * j);
            const unsigned k1 = (__float_as_uint(s2.y) & 0xFFFFFFC0u) | (unsigned)(2 * j + 1);
            wmA = umin32(wmA, k0);
            wmB = umin32(wmB, k1);
        }
        const unsigned wm = umin32(wmA, wmB);
        const unsigned base = jb + (unsigned)(wi * WLEN);   // scalar per window
        keyout[wi] = (wm & 0xFFFFE000u) | base | (wm & 63u);
    }

#pragma unroll
    for (int wi = 0; wi < NWIN; ++wi) mrg[w][wi][lane] = keyout[wi];
    __syncthreads();

    // stage 1: waves 0..3 each merge 4 slices' window minima (self filtered)
    if (w < 4) {
        const unsigned selfidx = (unsigned)qi;
        unsigned best[KNN];
#pragma unroll
        for (int s = 0; s < KNN; ++s) best[s] = 0xFFFFFFFFu;
        for (int sl = 4 * w; sl < 4 * w + 4; ++sl) {
#pragma unroll
            for (int u = 0; u < KNN; ++u) {
                unsigned key = mrg[sl][u][lane];
                key = ((key & 0x1FFFu) == selfidx) ? 0xFFFFFFFFu : key;
                INSERT8(best, key);
            }
        }
#pragma unroll
        for (int s = 0; s < KNN; ++s) mrg[4 * w][s][lane] = best[s];
    }
    __syncthreads();

    // stage 2: wave 0 merges the 4 partials; closed-form deviation sum
    if (w == 0) {
        unsigned best[KNN];
#pragma unroll
        for (int s = 0; s < KNN; ++s) best[s] = 0xFFFFFFFFu;
        for (int g = 0; g < 4; ++g) {
#pragma unroll
            for (int u = 0; u < KNN; ++u) {
                const unsigned key = mrg[4 * g][u][lane];
                INSERT8(best, key);
            }
        }
        float sx = 0.f, sy = 0.f, sz = 0.f, sw = 0.f;
#pragma unroll
        for (int s = 0; s < KNN; ++s) {
            const unsigned n = best[s] & 0x1FFFu;
            const float* np = B + (size_t)(n >> 1) * 8 + (n & 1);
            sx += np[0]; sy += np[2]; sz += np[4]; sw += np[6];
        }
        float ssum = sw - (sx * sx + sy * sy + sz * sz) * (1.f / KNN);
#pragma unroll
        for (int o = 32; o > 0; o >>= 1) ssum += __shfl_down(ssum, o, 64);
        if (lane == 0) atomicAdd(&acc[2], (double)ssum);
    }

    // last-done block finalizes the 5 outputs (prep finished before this kernel)
    __syncthreads();
    if (t == 0) {
        __threadfence();
        const unsigned old = atomicAdd(ctr, 1u);
        if (old == SCAN_BLOCKS - 1) {
            __threadfence();
            const double a0 = atomicAdd(&acc[0], 0.0);
            const double a1 = atomicAdd(&acc[1], 0.0);
            const double a2d = atomicAdd(&acc[2], 0.0);
            const double a3 = atomicAdd(&acc[3], 0.0);
            const double a4 = atomicAdd(&acc[4], 0.0);
            const double recon  = a0 / (double)(NBATCH * NPTS * 3);
            const double percep = a1 / 4096.0;
            const double cont   = a2d / (double)(NBATCH * NPTS * KNN);
            const double bnd    = (a4 > 0.0) ? a3 / ((a4 > 1.0) ? a4 : 1.0) : 0.0;
            const double total  = recon + 0.5 * percep + 0.5 * cont + bnd;
            out[0] = (float)recon;
            out[1] = (float)percep;
            out[2] = (float)cont;
            out[3] = (float)bnd;
            out[4] = (float)total;
        }
    }
}

extern "C" void kernel_launch(void* const* d_in, const int* in_sizes, int n_in,
                              void* d_out, int out_size, void* d_ws, size_t ws_size,
                              hipStream_t stream) {
    const float* pred = (const float*)d_in[0];
    const float* targ = (const float*)d_in[1];
    const float* pf   = (const float*)d_in[2];
    const float* tf   = (const float*)d_in[3];
    const float* c1   = (const float*)d_in[4];
    const float* c2   = (const float*)d_in[5];
    float* out  = (float*)d_out;
    double* acc = (double*)d_ws;
    unsigned* ctr = (unsigned*)((char*)d_ws + CTR_OFF);
    float* pb   = (float*)((char*)d_ws + PB_OFF);

    hipMemsetAsync(d_ws, 0, 64, stream);   // acc[0..4] + ctr
    hipLaunchKernelGGL(prep_kernel, dim3(146), dim3(512), 0, stream,
                       pred, c2, pred, targ, pf, tf, c1, pb, acc);
    hipLaunchKernelGGL(main_kernel, dim3(SCAN_BLOCKS), dim3(1024), 0, stream,
                       pb, acc, ctr, out);
}